// Round 7
// baseline (404.946 us; speedup 1.0000x reference)
//
#include <hip/hip_runtime.h>
#include <hip/hip_fp16.h>

// Tree NN: reps = emb[tokens] (4096 x 128 x 128); 7x: reps = tanh(concat(pairs) @ W_tree^T + b);
// out = root @ W_cls^T + b_cls.
//
// R20: TLP attack with R13's proven register shape. Evidence chain:
//  - R19 (clean, no spill): halved LDS reads -> SLOWER (85->109us) at 8 waves/CU.
//    LDS-pipe theory dead (corrected arithmetic: pipe was ~30% busy, not 90%).
//  - R13(12 w/CU)=85us vs R19(8 w/CU)=109us: time tracks 1/waves; all pipes <=35%.
//    => latency-bound 14-barrier chain; TLP is the lever. R15/R18 tried raising TLP
//    but spilled (lb cap < demand) and never tested it cleanly.
//  - R13's per-wave structure (Wf[2][8]=64 VGPR, 2 n-tiles) compiles to 72 VGPR.
//
// R20 = 8-wave blocks, wave (wm=wid>>2, wn=wid&3): wn owns 2 n-tiles (Wf[2][8], same
// 72-VGPR shape as R13; only delta is an mbase offset), wm splits m at L0/L1; tail
// levels (L2..L6) on wm0's 4 waves (they span all 128 cols). LDS unchanged 52.9 KB ->
// 3 blocks/CU x 8 waves = 24 waves/CU (6/SIMD), 2x R13. lb(512,6) caps VGPR ~85 >
// demand ~76-80 -> no spill expected. Gather: 512 threads, quarter-row each, loads and
// cvts interleaved (no staging arrays - R15's spill trigger).
// Spill gate (pre-committed): WRITE_SIZE ~96B / VGPR 76-84 = clean; MB-scale WRITE =>
// spilled => shrink Wf next. Clean + dur>=95us => TLP not the lever => pipeline samples.
//
// Kept: pair-contig LDS layout, conflict-free gather writes, fp16 MFMA 16x16x32 K-split
// 2x4 chains, bias in acc init, fp32 tanh/classifier, batched L5/L6, __syncthreads.

typedef _Float16 half8 __attribute__((ext_vector_type(8)));
typedef float floatx4 __attribute__((ext_vector_type(4)));

#define STRIDE 264   // 256 + 8 fp16 pad: A-row ds_read_b128 conflict-free
#define UROW   33    // uint4 per row
#define NPAIR  2048

__device__ __forceinline__ float fast_tanh(float x) {
  // No clamp needed: e=inf -> 1; e=0 -> -1. Inputs never NaN.
  float e = __expf(2.f * x);
  return 1.f - 2.f * __builtin_amdgcn_rcpf(e + 1.f);
}

__device__ __forceinline__ unsigned pkrtz(float a, float b) {
  auto h = __builtin_amdgcn_cvt_pkrtz(a, b);   // __fp16 ext_vector(2)
  return __builtin_bit_cast(unsigned, h);
}

// Gather, 512 threads: thread (row=t&63, seg=t>>6) covers leaf 2*row+(seg>>2),
// feature-quarter q=seg&3 (32 floats). Writes 4 uint4 at row*33 + (seg>>2)*16 + q*4:
// consecutive lanes hit consecutive rows (132B stride -> distinct banks per 16-lane
// phase) -> conflict-free. Loads/cvt interleaved: short live ranges, no staging array.
__device__ __forceinline__ void gather_quarter(int tok, const float* __restrict__ emb,
                                               _Float16* buf, int row, int seg) {
  const float4* src = (const float4*)emb + (size_t)tok * 32 + (seg & 3) * 8;
  uint4* dst = (uint4*)buf + row * UROW + (seg >> 2) * 16 + (seg & 3) * 4;
#pragma unroll
  for (int j = 0; j < 4; ++j) {
    float4 x = src[2 * j], y = src[2 * j + 1];
    uint4 w;
    w.x = pkrtz(x.x, x.y); w.y = pkrtz(x.z, x.w);
    w.z = pkrtz(y.x, y.y); w.w = pkrtz(y.z, y.w);
    dst[j] = w;
  }
}

// K=256 MFMA for one 16-row m-tile, 2 n-tiles, K-split into 2 independent 4-chains.
// Chain A initialized with bias (per-col, uniform across the 4 D-rows of a reg quad).
// A-frag: A[m=lane&15][k=quad*8+j]; B-frag: B[k=quad*8+j][n=lane&15];
// D: col=lane&15, row=quad*4+reg (verified layouts, learn_hip m89/m91).
__device__ __forceinline__ void mfma_k256(const _Float16* arow, const half8 (&Wf)[2][8],
                                          const float (&bias)[2], floatx4 (&accO)[2]) {
  floatx4 aA[2], aB[2];
#pragma unroll
  for (int i = 0; i < 2; ++i) {
    aA[i] = (floatx4){bias[i], bias[i], bias[i], bias[i]};
    aB[i] = (floatx4){0.f, 0.f, 0.f, 0.f};
  }
#pragma unroll
  for (int ks = 0; ks < 4; ++ks) {
    half8 x0 = *(const half8*)(arow + ks * 32);
    half8 x1 = *(const half8*)(arow + (ks + 4) * 32);
    aA[0] = __builtin_amdgcn_mfma_f32_16x16x32_f16(x0, Wf[0][ks],     aA[0], 0, 0, 0);
    aB[0] = __builtin_amdgcn_mfma_f32_16x16x32_f16(x1, Wf[0][ks + 4], aB[0], 0, 0, 0);
    aA[1] = __builtin_amdgcn_mfma_f32_16x16x32_f16(x0, Wf[1][ks],     aA[1], 0, 0, 0);
    aB[1] = __builtin_amdgcn_mfma_f32_16x16x32_f16(x1, Wf[1][ks + 4], aB[1], 0, 0, 0);
  }
  accO[0] = aA[0] + aB[0];
  accO[1] = aA[1] + aB[1];
}

// One wave: its 2 n-tiles for MT_LOC m-tiles starting at mbase. Pair-contiguous store,
// MOUT row mask. Stale rows above MOUT hold finite tanh/leaf values; masked at store.
template<int MT_LOC, int MOUT>
__device__ __forceinline__ void level_ms(
    const _Float16* inb, _Float16* outb,
    const half8 (&Wf)[2][8], const float (&bias)[2],
    int mbase, int nbase, int l15, int quad)
{
#pragma unroll
  for (int m = 0; m < MT_LOC; ++m) {
    floatx4 acc[2];
    mfma_k256(inb + ((mbase + m) * 16 + l15) * STRIDE + quad * 8, Wf, bias, acc);
    const int mrow = (mbase + m) * 16 + quad * 4;
#pragma unroll
    for (int i = 0; i < 2; ++i) {
      const int col = (nbase + i) * 16 + l15;
#pragma unroll
      for (int r = 0; r < 4; ++r) {
        const int node = mrow + r;
        if (MOUT == 64 || node < MOUT) {   // compile-time short-circuit for L0
          float v = fast_tanh(acc[i][r]);
          outb[(node >> 1) * STRIDE + (node & 1) * 128 + col] = (_Float16)v;
        }
      }
    }
  }
}

__global__ __launch_bounds__(512, 6)   // 8 waves/block, 6 waves/SIMD: cap ~85 > demand ~80
void tree_kernel(const int* __restrict__ tokens,
                 const float* __restrict__ embedding,
                 const float* __restrict__ W_tree,
                 const float* __restrict__ b_tree,
                 const float* __restrict__ W_cls,
                 const float* __restrict__ b_cls,
                 float* __restrict__ out)
{
  __shared__ __align__(16) _Float16 bufA[64 * STRIDE];   // leaves / even outputs (33.8 KB)
  __shared__ __align__(16) _Float16 bufB[32 * STRIDE];   // odd outputs (16.9 KB)
  __shared__ __align__(16) _Float16 bufC[4 * STRIDE];    // pair stash: L4 outs (2.1 KB)
  __shared__ float wavepart[4][2][3];                    // classifier partials (96 B)

  const int tid  = threadIdx.x;
  const int wid  = tid >> 6;               // wave id 0-7
  const int lane = tid & 63;
  const int l15  = lane & 15;
  const int quad = lane >> 4;
  const int wn   = wid & 3;                // n-quarter: cols [32*wn, 32*wn+32)
  const int wm   = wid >> 2;               // m-half for L0/L1; wm0 runs the tail
  const int nbase = wn * 2;
  const int row  = tid & 63;               // gather destination row
  const int seg  = tid >> 6;               // gather segment 0-7
  const int tidx = 2 * row + (seg >> 2);   // this thread's token index within a sample

  // ---- stage this wave's 2 n-tiles of W_tree as B-fragments (64 VGPR) ----
  // B[k][n] = W_tree[e=n][h=k]  (einsum 'bnh,eh->bne' => out = comb @ W^T)
  half8 Wf[2][8];
#pragma unroll
  for (int i = 0; i < 2; ++i) {
    const int e = (nbase + i) * 16 + l15;
#pragma unroll
    for (int ks = 0; ks < 8; ++ks) {
      const int k = ks * 32 + quad * 8;
      const float4* p = (const float4*)(W_tree + e * 256 + k);
      float4 lo = p[0], hi = p[1];
      half8 f;
      f[0] = (_Float16)lo.x; f[1] = (_Float16)lo.y; f[2] = (_Float16)lo.z; f[3] = (_Float16)lo.w;
      f[4] = (_Float16)hi.x; f[5] = (_Float16)hi.y; f[6] = (_Float16)hi.z; f[7] = (_Float16)hi.w;
      Wf[i][ks] = f;
    }
  }
  float bias[2];
#pragma unroll
  for (int i = 0; i < 2; ++i) bias[i] = b_tree[(nbase + i) * 16 + l15];

  int tokA = tokens[(2 * blockIdx.x) * 128 + tidx];       // preloaded pair tokens
  int tokB = tokens[(2 * blockIdx.x + 1) * 128 + tidx];

#pragma unroll 1
  for (int p = blockIdx.x; p < NPAIR; p += gridDim.x) {
    int pn = p + gridDim.x;
    if (pn >= NPAIR) pn = p;               // last iteration: harmless self-reload

    // ---- s0 gather (token preloaded) + preload next-pair tokens ----
    gather_quarter(tokA, embedding, bufA, row, seg);
    const int tokAn = tokens[(2 * pn) * 128 + tidx];
    const int tokBn = tokens[(2 * pn + 1) * 128 + tidx];
    __syncthreads();

    // ---- s0 levels: L0..L4, stash L4-out in bufC rows 0-1 ----
    level_ms<2, 64>(bufA, bufB, Wf, bias, wm * 2, nbase, l15, quad);   // L0: wm-split
    __syncthreads();
    level_ms<1, 32>(bufB, bufA, Wf, bias, wm,     nbase, l15, quad);   // L1: wm-split
    __syncthreads();
    if (wm == 0) level_ms<1, 16>(bufA, bufB, Wf, bias, 0, nbase, l15, quad);  // L2
    __syncthreads();
    if (wm == 0) level_ms<1,  8>(bufB, bufA, Wf, bias, 0, nbase, l15, quad);  // L3
    __syncthreads();
    if (wm == 0) level_ms<1,  4>(bufA, bufC, Wf, bias, 0, nbase, l15, quad);  // L4
    __syncthreads();

    // ---- s1 gather ----
    gather_quarter(tokB, embedding, bufA, row, seg);
    __syncthreads();

    // ---- s1 levels: L0..L4, stash L4-out in bufC rows 2-3 ----
    level_ms<2, 64>(bufA, bufB, Wf, bias, wm * 2, nbase, l15, quad);   // L0
    __syncthreads();
    level_ms<1, 32>(bufB, bufA, Wf, bias, wm,     nbase, l15, quad);   // L1
    __syncthreads();
    if (wm == 0) level_ms<1, 16>(bufA, bufB, Wf, bias, 0, nbase, l15, quad);  // L2
    __syncthreads();
    if (wm == 0) level_ms<1,  8>(bufB, bufA, Wf, bias, 0, nbase, l15, quad);  // L3
    __syncthreads();
    if (wm == 0) level_ms<1,  4>(bufA, bufC + 2 * STRIDE, Wf, bias, 0, nbase, l15, quad); // L4
    __syncthreads();

    // ---- batched L5 (wm0): bufC rows 0-3 -> bufA rows 0-1 ----
    if (wm == 0) {
      const int rclamp = l15 < 4 ? l15 : 3;          // bufC bounds; rows>=4 discarded
      floatx4 acc[2];
      mfma_k256(bufC + rclamp * STRIDE + quad * 8, Wf, bias, acc);
      const int mrow = quad * 4;
#pragma unroll
      for (int i = 0; i < 2; ++i) {
        const int col = (nbase + i) * 16 + l15;
#pragma unroll
        for (int r = 0; r < 4; ++r) {
          const int mr = mrow + r;                   // mr<4 valid: sample mr>>1, node mr&1
          if (mr < 4) {
            float v = fast_tanh(acc[i][r]);
            bufA[(mr >> 1) * STRIDE + (mr & 1) * 128 + col] = (_Float16)v;
          }
        }
      }
    }
    __syncthreads();

    // ---- batched L6 + classifier partials (wm0) ----
    if (wm == 0) {
      // classifier weights reloaded per pair (keeps them out of the permanent set)
      float wc[2][3];
#pragma unroll
      for (int i = 0; i < 2; ++i)
#pragma unroll
        for (int o = 0; o < 3; ++o) wc[i][o] = W_cls[o * 128 + (nbase + i) * 16 + l15];

      floatx4 acc[2];
      mfma_k256(bufA + l15 * STRIDE + quad * 8, Wf, bias, acc); // rows 0-1 = roots s0,s1
      float part[2][3] = {{0.f, 0.f, 0.f}, {0.f, 0.f, 0.f}};
      if (quad == 0) {
#pragma unroll
        for (int i = 0; i < 2; ++i)
#pragma unroll
          for (int rr = 0; rr < 2; ++rr) {           // rr = sample
            float v = fast_tanh(acc[i][rr]);
#pragma unroll
            for (int o = 0; o < 3; ++o) part[rr][o] = fmaf(v, wc[i][o], part[rr][o]);
          }
      }
#pragma unroll
      for (int rr = 0; rr < 2; ++rr)
#pragma unroll
        for (int o = 0; o < 3; ++o) {
          float v = part[rr][o];                     // nonzero only in quad-0 lanes
          v += __shfl_down(v, 8);
          v += __shfl_down(v, 4);
          v += __shfl_down(v, 2);
          v += __shfl_down(v, 1);
          if (lane == 0) wavepart[wn][rr][o] = v;
        }
    }
    __syncthreads();
    if (tid < 6) {
      const int rr = tid / 3, o = tid - 3 * rr;
      float v = wavepart[0][rr][o] + wavepart[1][rr][o]
              + wavepart[2][rr][o] + wavepart[3][rr][o];
      out[(2 * p + rr) * 3 + o] = v + b_cls[o];
    }
    tokA = tokAn; tokB = tokBn;
    // next pair's gather overwrites bufA: all L6 bufA reads completed before the wavepart
    // barrier; wavepart next written 14 barriers later -> safe.
  }
}

extern "C" void kernel_launch(void* const* d_in, const int* in_sizes, int n_in,
                              void* d_out, int out_size, void* d_ws, size_t ws_size,
                              hipStream_t stream) {
  const int*   tokens    = (const int*)d_in[0];
  const float* embedding = (const float*)d_in[1];
  const float* W_tree    = (const float*)d_in[2];
  const float* b_tree    = (const float*)d_in[3];
  const float* W_cls     = (const float*)d_in[4];
  const float* b_cls     = (const float*)d_in[5];
  float* out = (float*)d_out;

  dim3 grid(768), block(512);   // 3 blocks/CU x 256 CUs; 24 waves/CU; grid-stride 2048 pairs
  tree_kernel<<<grid, block, 0, stream>>>(tokens, embedding, W_tree, b_tree, W_cls, b_cls, out);
}

// Round 8
// 163.989 us; speedup vs baseline: 2.4694x; 2.4694x over previous
//
#include <hip/hip_runtime.h>
#include <hip/hip_fp16.h>

// Tree NN: reps = emb[tokens] (4096 x 128 x 128); 7x: reps = tanh(concat(pairs) @ W_tree^T + b);
// out = root @ W_cls^T + b_cls.
//
// R21: PHASE-COUNT attack. Model from all clean runs: wall = phases/block x ~2us/phase,
// phase cost ~constant vs blocks/CU and wave tiling (R13: 42ph x 2.02 = 85us; R19: 56 x
// 1.95 = 109us). Each ~2us phase holds ~1us of issue work; the rest is the barrier-synced
// chain latency. TLP via 512-thread blocks is closed (R15/R18/R20 all spilled: Wf+acc+
// staging cannot fit high waves/EU VGPR caps). So: cut phases/pair 14 -> 8:
//  1. BATCH L2..L5 ACROSS THE PAIR (M=32,16,8,8-masked): both samples' tail rows packed
//     in one buffer -> per-sample L2/L3/L4 phases vanish, tail = 4 phases.
//     Generic store: input row R of batched level (IN_S rows/sample): s=R/IN_S, ln=R%IN_S,
//     out-row=(ln>>1)+s*(IN_S>>1), col-half=ln&1. All tail inputs fully written by
//     producer phase (stale m-tile rows masked at store; always finite).
//  2. MERGE GATHERS INTO L1 PHASES: L1 reads B writes D, gather writes A -> disjoint.
//     Stage 16xfloat4 to regs, run L1 (hides ~600cy load latency), cvt+ds_write, barrier.
//  3. DEFER L6 one iteration, merged into next pair's L0 phase (L6 reads D[0:2], L0 reads
//     A writes B -> disjoint). out-store for prev pair folded into ph_b.
// Schedule/pair: phA{L6(prev)+L0 s0} phB{out(prev)+L1 s0+gather s1} phC{L0 s1}
//   phD{L1 s1+gather s0'} phE{L2b} phF{L3b} phG{L4b} phH{L5b}  = 8 barriers.
// LDS: A 64 + B 32 + D 32 rows = 67.6KB -> 2 blocks/CU; grid 512 = exactly 4 pairs/block.
// lb(256,2): cap 256 VGPR, peak demand ~180 (Wf 64 + staging 64 + acc + addr) -> the
// proven-clean regime (R19). Per-wave structure = R13 (4 waves n-split, Wf[2][8], K-split
// 2x4 MFMA chains, bias in acc init).
// Pre-committed: no-spill gate VGPR 170-200 / WRITE ~96B / FETCH ~123MB. Clean + 64-75us
// = model confirmed. Clean + >=85us = phase-model wrong -> attack per-phase latency next.

typedef _Float16 half8 __attribute__((ext_vector_type(8)));
typedef float floatx4 __attribute__((ext_vector_type(4)));

#define STRIDE 264   // 256 + 8 fp16 pad: A-row ds_read_b128 conflict-free
#define UROW   33    // uint4 per row
#define NPAIR  2048

__device__ __forceinline__ float fast_tanh(float x) {
  // No clamp needed: e=inf -> 1; e=0 -> -1. Inputs never NaN.
  float e = __expf(2.f * x);
  return 1.f - 2.f * __builtin_amdgcn_rcpf(e + 1.f);
}

__device__ __forceinline__ unsigned pkrtz(float a, float b) {
  auto h = __builtin_amdgcn_cvt_pkrtz(a, b);   // __fp16 ext_vector(2)
  return __builtin_bit_cast(unsigned, h);
}

// Gather split into issue (load16 -> 64 VGPR staging) and commit (cvt + 8 uint4 writes).
// Thread (row=t&63, seg=t>>6) covers leaf 2*row+(seg>>1), feature-half seg&1; 8
// consecutive lanes hit 8 consecutive rows -> conflict-free writes. Pair-contig layout.
__device__ __forceinline__ void load16(const float* __restrict__ emb, int tok, int seg,
                                       float4 (&st)[16]) {
  const float4* src = (const float4*)emb + (size_t)tok * 32 + (seg & 1) * 16;
#pragma unroll
  for (int j = 0; j < 16; ++j) st[j] = src[j];
}
__device__ __forceinline__ void cvt_write(const float4 (&st)[16], _Float16* buf,
                                          int row, int seg) {
  uint4* dst = (uint4*)buf + row * UROW + seg * 8;
#pragma unroll
  for (int j = 0; j < 8; ++j) {
    float4 x = st[2 * j], y = st[2 * j + 1];
    uint4 w;
    w.x = pkrtz(x.x, x.y); w.y = pkrtz(x.z, x.w);
    w.z = pkrtz(y.x, y.y); w.w = pkrtz(y.z, y.w);
    dst[j] = w;
  }
}

// K=256 MFMA for one 16-row m-tile, 2 n-tiles, K-split into 2 independent 4-chains.
// Chain A initialized with bias. A-frag: A[m=lane&15][k=quad*8+j]; B-frag:
// B[k=quad*8+j][n=lane&15]; D: col=lane&15, row=quad*4+reg (learn_hip m89/m91).
__device__ __forceinline__ void mfma_k256(const _Float16* arow, const half8 (&Wf)[2][8],
                                          const float (&bias)[2], floatx4 (&accO)[2]) {
  floatx4 aA[2], aB[2];
#pragma unroll
  for (int i = 0; i < 2; ++i) {
    aA[i] = (floatx4){bias[i], bias[i], bias[i], bias[i]};
    aB[i] = (floatx4){0.f, 0.f, 0.f, 0.f};
  }
#pragma unroll
  for (int ks = 0; ks < 4; ++ks) {
    half8 x0 = *(const half8*)(arow + ks * 32);
    half8 x1 = *(const half8*)(arow + (ks + 4) * 32);
    aA[0] = __builtin_amdgcn_mfma_f32_16x16x32_f16(x0, Wf[0][ks],     aA[0], 0, 0, 0);
    aB[0] = __builtin_amdgcn_mfma_f32_16x16x32_f16(x1, Wf[0][ks + 4], aB[0], 0, 0, 0);
    aA[1] = __builtin_amdgcn_mfma_f32_16x16x32_f16(x0, Wf[1][ks],     aA[1], 0, 0, 0);
    aB[1] = __builtin_amdgcn_mfma_f32_16x16x32_f16(x1, Wf[1][ks + 4], aB[1], 0, 0, 0);
  }
  accO[0] = aA[0] + aB[0];
  accO[1] = aA[1] + aB[1];
}

// Batched level: MT m-tiles; input row R (< MVALID) maps to sample s=R/IN_S, local
// input-row ln=R%IN_S (holds concat of nodes 2ln,2ln+1 -> out-node ln of sample s).
// Store: out-row (ln>>1)+s*(IN_S>>1), col-half ln&1. Rows >= MVALID are stale (finite
// tanh/leaf values from earlier phases) and masked at store.
template<int MT, int IN_S, int MVALID>
__device__ __forceinline__ void level_b(const _Float16* inb, _Float16* outb,
                                        const half8 (&Wf)[2][8], const float (&bias)[2],
                                        int nbase, int l15, int quad)
{
#pragma unroll
  for (int m = 0; m < MT; ++m) {
    floatx4 acc[2];
    mfma_k256(inb + (m * 16 + l15) * STRIDE + quad * 8, Wf, bias, acc);
    const int mrow = m * 16 + quad * 4;
#pragma unroll
    for (int i = 0; i < 2; ++i) {
      const int col = (nbase + i) * 16 + l15;
#pragma unroll
      for (int r = 0; r < 4; ++r) {
        const int node = mrow + r;
        if (MVALID == MT * 16 || node < MVALID) {
          const int s  = node / IN_S;          // IN_S is a power of 2 -> shifts
          const int ln = node % IN_S;
          float v = fast_tanh(acc[i][r]);
          outb[((ln >> 1) + s * (IN_S >> 1)) * STRIDE + (ln & 1) * 128 + col] = (_Float16)v;
        }
      }
    }
  }
}

__global__ __launch_bounds__(256, 2)   // cap 256 VGPR: peak ~180 fits with slack (no spill)
void tree_kernel(const int* __restrict__ tokens,
                 const float* __restrict__ embedding,
                 const float* __restrict__ W_tree,
                 const float* __restrict__ b_tree,
                 const float* __restrict__ W_cls,
                 const float* __restrict__ b_cls,
                 float* __restrict__ out)
{
  __shared__ __align__(16) _Float16 bufA[64 * STRIDE];   // leaves (33.8 KB)
  __shared__ __align__(16) _Float16 bufB[32 * STRIDE];   // L0-out / tail ping (16.9 KB)
  __shared__ __align__(16) _Float16 bufD[32 * STRIDE];   // L1-outs both samples / tail pong (16.9 KB)
  __shared__ float wavepart[4][2][3];                    // classifier partials (96 B)

  const int tid  = threadIdx.x;
  const int wid  = tid >> 6;
  const int lane = tid & 63;
  const int l15  = lane & 15;
  const int quad = lane >> 4;
  const int nbase = wid * 2;               // this wave's n-tile base (cols [32*wid, +32))
  const int row  = tid & 63;               // gather destination row
  const int seg  = tid >> 6;               // gather leaf-half / feature-half segment
  const int tidx = 2 * row + (seg >> 1);   // this thread's token index within a sample

  // ---- stage this wave's 2 n-tiles of W_tree as B-fragments (64 VGPR) ----
  // B[k][n] = W_tree[e=n][h=k]  (einsum 'bnh,eh->bne' => out = comb @ W^T)
  half8 Wf[2][8];
#pragma unroll
  for (int i = 0; i < 2; ++i) {
    const int e = (nbase + i) * 16 + l15;
#pragma unroll
    for (int ks = 0; ks < 8; ++ks) {
      const int k = ks * 32 + quad * 8;
      const float4* p = (const float4*)(W_tree + e * 256 + k);
      float4 lo = p[0], hi = p[1];
      half8 f;
      f[0] = (_Float16)lo.x; f[1] = (_Float16)lo.y; f[2] = (_Float16)lo.z; f[3] = (_Float16)lo.w;
      f[4] = (_Float16)hi.x; f[5] = (_Float16)hi.y; f[6] = (_Float16)hi.z; f[7] = (_Float16)hi.w;
      Wf[i][ks] = f;
    }
  }
  float bias[2];
#pragma unroll
  for (int i = 0; i < 2; ++i) bias[i] = b_tree[(nbase + i) * 16 + l15];

  // classifier weights for this lane's 2 columns: loop-invariant (6 VGPR)
  float wc[2][3];
#pragma unroll
  for (int i = 0; i < 2; ++i) {
#pragma unroll
    for (int o = 0; o < 3; ++o) wc[i][o] = W_cls[o * 128 + (nbase + i) * 16 + l15];
  }

  // ---- prologue: gather s0 of first pair ----
  int tokB_cur = tokens[(2 * blockIdx.x + 1) * 128 + tidx];
  {
    const int tokA0 = tokens[(2 * blockIdx.x) * 128 + tidx];
    float4 st[16];
    load16(embedding, tokA0, seg, st);
    cvt_write(st, bufA, row, seg);
  }
  __syncthreads();

#pragma unroll 1
  for (int p = blockIdx.x; p < NPAIR; p += gridDim.x) {
    int pn = p + gridDim.x;
    if (pn >= NPAIR) pn = p;                   // last iter: harmless self-reload
    const bool first = (p == (int)blockIdx.x);
    const int pprev = p - (int)gridDim.x;
    const int tokA_nxt = tokens[(2 * pn) * 128 + tidx];
    const int tokB_nxt = tokens[(2 * pn + 1) * 128 + tidx];

    // ---- phA: L6b(prev pair, D rows 0-1) + classifier partials; L0 s0: A -> B ----
    if (!first) {
      floatx4 acc[2];
      mfma_k256(bufD + l15 * STRIDE + quad * 8, Wf, bias, acc);  // rows 0-1 = roots
      float part[2][3] = {{0.f, 0.f, 0.f}, {0.f, 0.f, 0.f}};
      if (quad == 0) {
#pragma unroll
        for (int i = 0; i < 2; ++i)
#pragma unroll
          for (int rr = 0; rr < 2; ++rr) {     // rr = sample
            float v = fast_tanh(acc[i][rr]);
#pragma unroll
            for (int o = 0; o < 3; ++o) part[rr][o] = fmaf(v, wc[i][o], part[rr][o]);
          }
      }
#pragma unroll
      for (int rr = 0; rr < 2; ++rr)
#pragma unroll
        for (int o = 0; o < 3; ++o) {
          float v = part[rr][o];               // nonzero only in quad-0 lanes
          v += __shfl_down(v, 8);
          v += __shfl_down(v, 4);
          v += __shfl_down(v, 2);
          v += __shfl_down(v, 1);
          if (lane == 0) wavepart[wid][rr][o] = v;
        }
    }
    level_b<4, 64, 64>(bufA, bufB, Wf, bias, nbase, l15, quad);    // L0 s0
    __syncthreads();

    // ---- phB: out-store(prev); L1 s0: B -> D[0:16]; gather s1 -> A (staged) ----
    {
      float4 st[16];
      load16(embedding, tokB_cur, seg, st);    // issue first: latency under L1
      if (!first && tid < 6) {
        const int rr = tid / 3, o = tid - 3 * rr;
        float v = wavepart[0][rr][o] + wavepart[1][rr][o]
                + wavepart[2][rr][o] + wavepart[3][rr][o];
        out[(2 * pprev + rr) * 3 + o] = v + b_cls[o];
      }
      level_b<2, 32, 32>(bufB, bufD, Wf, bias, nbase, l15, quad);  // L1 s0
      cvt_write(st, bufA, row, seg);
    }
    __syncthreads();

    // ---- phC: L0 s1: A -> B ----
    level_b<4, 64, 64>(bufA, bufB, Wf, bias, nbase, l15, quad);
    __syncthreads();

    // ---- phD: L1 s1: B -> D[16:32]; gather s0(next pair) -> A (staged) ----
    {
      float4 st[16];
      load16(embedding, tokA_nxt, seg, st);
      level_b<2, 32, 32>(bufB, bufD + 16 * STRIDE, Wf, bias, nbase, l15, quad);
      cvt_write(st, bufA, row, seg);
    }
    __syncthreads();

    // ---- phE: L2b: D[0:32] (s0 rows 0-15, s1 16-31) -> B[0:16] ----
    level_b<2, 16, 32>(bufD, bufB, Wf, bias, nbase, l15, quad);
    __syncthreads();

    // ---- phF: L3b: B[0:16] -> D[0:8] ----
    level_b<1, 8, 16>(bufB, bufD, Wf, bias, nbase, l15, quad);
    __syncthreads();

    // ---- phG: L4b: D[0:8] -> B[0:4]  (m-tile rows 8-15 stale, masked) ----
    level_b<1, 4, 8>(bufD, bufB, Wf, bias, nbase, l15, quad);
    __syncthreads();

    // ---- phH: L5b: B[0:4] -> D[0:2]  (rows 4-15 stale, masked) ----
    level_b<1, 2, 4>(bufB, bufD, Wf, bias, nbase, l15, quad);
    __syncthreads();

    tokB_cur = tokB_nxt;
  }

  // ---- epilogue: L6b + classifier + store for the final pair ----
  {
    const int plast = (int)blockIdx.x + ((NPAIR / 1 - 1 - (int)blockIdx.x) / (int)gridDim.x) * (int)gridDim.x;
    floatx4 acc[2];
    mfma_k256(bufD + l15 * STRIDE + quad * 8, Wf, bias, acc);
    float part[2][3] = {{0.f, 0.f, 0.f}, {0.f, 0.f, 0.f}};
    if (quad == 0) {
#pragma unroll
      for (int i = 0; i < 2; ++i)
#pragma unroll
        for (int rr = 0; rr < 2; ++rr) {
          float v = fast_tanh(acc[i][rr]);
#pragma unroll
          for (int o = 0; o < 3; ++o) part[rr][o] = fmaf(v, wc[i][o], part[rr][o]);
        }
    }
#pragma unroll
    for (int rr = 0; rr < 2; ++rr)
#pragma unroll
      for (int o = 0; o < 3; ++o) {
        float v = part[rr][o];
        v += __shfl_down(v, 8);
        v += __shfl_down(v, 4);
        v += __shfl_down(v, 2);
        v += __shfl_down(v, 1);
        if (lane == 0) wavepart[wid][rr][o] = v;
      }
    __syncthreads();
    if (tid < 6) {
      const int rr = tid / 3, o = tid - 3 * rr;
      float v = wavepart[0][rr][o] + wavepart[1][rr][o]
              + wavepart[2][rr][o] + wavepart[3][rr][o];
      out[(2 * plast + rr) * 3 + o] = v + b_cls[o];
    }
  }
}

extern "C" void kernel_launch(void* const* d_in, const int* in_sizes, int n_in,
                              void* d_out, int out_size, void* d_ws, size_t ws_size,
                              hipStream_t stream) {
  const int*   tokens    = (const int*)d_in[0];
  const float* embedding = (const float*)d_in[1];
  const float* W_tree    = (const float*)d_in[2];
  const float* b_tree    = (const float*)d_in[3];
  const float* W_cls     = (const float*)d_in[4];
  const float* b_cls     = (const float*)d_in[5];
  float* out = (float*)d_out;

  dim3 grid(512), block(256);   // 2 blocks/CU x 256 CUs (LDS 67.6KB); exactly 4 pairs/block
  tree_kernel<<<grid, block, 0, stream>>>(tokens, embedding, W_tree, b_tree, W_cls, b_cls, out);
}